// Round 9
// baseline (565.158 us; speedup 1.0000x reference)
//
#include <hip/hip_runtime.h>
#include <hip/hip_bf16.h>

// LocalAggregation: B=8, N=2048, K=32, D=64, C1=64, C2=128, R=0.15, EPS=1e-5
// f32 storage, bf16-ified values.
// Factored stats1 (validated R7/R8):
//   h1[row,c] = g[m,c] + dx*wx[c]+dy*wy[c]+dz*wz[c],  g = feat @ W1[3:]
//   sum1[c]   = SUM_m cnt[m] g[m,c] + wx M1x + wy M1y + wz M1z
//   sumsq1[c] = SUM_m cnt g^2 + 2(wx A3x + wy A3y + wz A3z) + quadratic moments
// R9: kP uses __hip_atomic_fetch_add (WORKGROUP scope -> ds_add_f32; plain
//     atomicAdd on LDS float was a CAS loop -> 88 us @ 0.4% VALU). 256 blocks
//     x 512 thr. kB is now MFMA (g-GEMM) with fused A-sums. kD at (256,4).
//     k4/k5 merged. gamma2>0 => max-pool commutes with bn2+relu (k45).

#define BB 8
#define NN 2048
#define KK 32
#define DD 64
#define CC1 64
#define CC2 128
#define TOTROWS (BB*NN*KK) // 524288
#define SITES (BB*NN)      // 16384

typedef __bf16 bf16x8 __attribute__((ext_vector_type(8)));
typedef float  f32x4  __attribute__((ext_vector_type(4)));

__device__ __forceinline__ void lds_add(float* p, float v) {
  __hip_atomic_fetch_add(p, v, __ATOMIC_RELAXED, __HIP_MEMORY_SCOPE_WORKGROUP);
}

// ---------------- K1: ball query, ballot compaction ----------------
// 512 blocks x 256 thr; block = (batch, 32-query group), wave = 8 queries.
__global__ __launch_bounds__(256) void k1_ball(const float* __restrict__ pos,
                                               int* __restrict__ idx)
{
  __shared__ float4 P[NN];  // 32 KB: x,y,z,S
  const int b = blockIdx.x >> 6;
  const int qbase = (blockIdx.x & 63) * 32;
  for (int i = threadIdx.x; i < NN; i += 256) {
    const float* p = pos + ((size_t)b*NN + i)*3;
    float x = p[0], y = p[1], z = p[2];
    float s = __fadd_rn(__fadd_rn(__fmul_rn(x,x), __fmul_rn(y,y)), __fmul_rn(z,z));
    P[i] = make_float4(x, y, z, s);
  }
  __syncthreads();
  const int wave = threadIdx.x >> 6, lane = threadIdx.x & 63;
  const float R2 = (float)(0.15 * 0.15);
  const unsigned long long lt = (lane == 63) ? 0x7fffffffffffffffull
                                             : ((1ull << lane) - 1ull);
  for (int qi = wave; qi < 32; qi += 4) {
    const int q = qbase + qi;
    const float4 Q = P[q];
    int* ip = idx + ((size_t)b*NN + q)*KK;
    int cnt = 0, first = -1;
    for (int step = 0; step < 32; ++step) {
      float4 p = P[step*64 + lane];
      float d = __fmul_rn(Q.x, p.x);
      d = fmaf(Q.y, p.y, d);
      d = fmaf(Q.z, p.z, d);
      float sq = __fsub_rn(__fadd_rn(Q.w, p.w), __fmul_rn(2.0f, d));
      bool in = !(sq > R2);
      unsigned long long mask = __ballot(in);
      if (first < 0 && mask) first = step*64 + (int)__builtin_ctzll(mask);
      int dst = cnt + (int)__popcll(mask & lt);
      if (in && dst < KK) ip[dst] = step*64 + lane;
      cnt += (int)__popcll(mask);
      if (cnt >= KK) break;
    }
    if (lane >= cnt && lane < KK) ip[lane] = first;  // cnt>=1 (self in ball)
  }
}

// ---------------- KP: per-m scatter + global moments ----------------
// 256 blocks x 512 thr; block = (batch, 64-site slice). All pairs (incl.
// padding duplicates) iterated via idx. LDS accumulators via ds_add_f32.
__global__ __launch_bounds__(512) void kP_scatter(
    const float* __restrict__ pos, const int* __restrict__ idx,
    float* __restrict__ cnt, float* __restrict__ DXa,
    float* __restrict__ DYa, float* __restrict__ DZa,
    float* __restrict__ mom)
{
  __shared__ float Sc[NN], Sx[NN], Sy[NN], Sz[NN];  // 32 KB
  const int b = blockIdx.x >> 5;
  const int slice = blockIdx.x & 31;   // 64 sites
  for (int i = threadIdx.x; i < NN; i += 512) {
    Sc[i] = 0.f; Sx[i] = 0.f; Sy[i] = 0.f; Sz[i] = 0.f;
  }
  __syncthreads();
  const float* pb = pos + (size_t)b*NN*3;
  const int* ip = idx + ((size_t)(b*NN + slice*64))*KK;
  float m1x=0.f,m1y=0.f,m1z=0.f,mxx=0.f,myy=0.f,mzz=0.f,mxy=0.f,mxz=0.f,myz=0.f;
  #pragma unroll
  for (int it = 0; it < 4; ++it) {     // 64*32 = 2048 pairs / 512 thr
    int flat = it*512 + threadIdx.x;
    int m  = ip[flat];
    int cs = slice*64 + (flat >> 5);
    float dx = pb[m*3  ] - pb[cs*3  ];
    float dy = pb[m*3+1] - pb[cs*3+1];
    float dz = pb[m*3+2] - pb[cs*3+2];
    lds_add(&Sc[m], 1.0f);
    lds_add(&Sx[m], dx);
    lds_add(&Sy[m], dy);
    lds_add(&Sz[m], dz);
    m1x += dx; m1y += dy; m1z += dz;
    mxx = fmaf(dx,dx,mxx); myy = fmaf(dy,dy,myy); mzz = fmaf(dz,dz,mzz);
    mxy = fmaf(dx,dy,mxy); mxz = fmaf(dx,dz,mxz); myz = fmaf(dy,dz,myz);
  }
  __syncthreads();
  for (int i = threadIdx.x; i < NN; i += 512) {
    unsafeAtomicAdd(&cnt[b*NN + i], Sc[i]);
    unsafeAtomicAdd(&DXa[b*NN + i], Sx[i]);
    unsafeAtomicAdd(&DYa[b*NN + i], Sy[i]);
    unsafeAtomicAdd(&DZa[b*NN + i], Sz[i]);
  }
  const int lane = threadIdx.x & 63;
  float vals[9] = {m1x,m1y,m1z,mxx,myy,mzz,mxy,mxz,myz};
  #pragma unroll
  for (int i = 0; i < 9; ++i) {
    float v = vals[i];
    #pragma unroll
    for (int s = 1; s < 64; s <<= 1) v += __shfl_xor(v, s, 64);
    if (lane == 0) unsafeAtomicAdd(&mom[i], v);
  }
}

// ---------------- KB: g = feat @ W1[3:] via MFMA, fused A-sums ----------------
// 128 blocks x 256 thr -> 512 waves x 2 M-tiles (16 rows each).
// A-frag: lane holds feat[row0+col][quad*8+j]; B-frag: W1f[k][nt*16+col];
// C/D: col=lane&15, row=quad*4+r (m89-verified).
// A layout: [0:64) Sum cnt*g, [64:128) Sum cnt*g^2, [128:192) Sum g*DX,
//           [192:256) Sum g*DY, [256:320) Sum g*DZ
__global__ __launch_bounds__(256) void kB_g(const float* __restrict__ feat,
                                            const float* __restrict__ W1,
                                            const float* __restrict__ cnt,
                                            const float* __restrict__ DXa,
                                            const float* __restrict__ DYa,
                                            const float* __restrict__ DZa,
                                            float* __restrict__ g,
                                            float* __restrict__ A)
{
  __shared__ float red[320];
  for (int i = threadIdx.x; i < 320; i += 256) red[i] = 0.f;
  __syncthreads();
  const int lane = threadIdx.x & 63;
  const int quad = lane >> 4;
  const int col  = lane & 15;
  const int gw = (blockIdx.x*256 + threadIdx.x) >> 6;   // 0..511

  bf16x8 Bf[2][4];
  #pragma unroll
  for (int kt = 0; kt < 2; ++kt)
    #pragma unroll
    for (int nt = 0; nt < 4; ++nt) {
      bf16x8 v;
      #pragma unroll
      for (int j = 0; j < 8; ++j)
        v[j] = (__bf16)W1[(3 + kt*32 + quad*8 + j)*CC1 + nt*16 + col];
      Bf[kt][nt] = v;
    }
  float a1[4], a2[4], a3[4], a4[4], a5[4];
  #pragma unroll
  for (int nt = 0; nt < 4; ++nt) { a1[nt]=0.f; a2[nt]=0.f; a3[nt]=0.f; a4[nt]=0.f; a5[nt]=0.f; }

  for (int t = 0; t < 2; ++t) {
    const int row0 = (gw*2 + t) * 16;
    bf16x8 Af[2];
    #pragma unroll
    for (int kt = 0; kt < 2; ++kt) {
      const float4* fp =
        (const float4*)(feat + (size_t)(row0 + col)*DD + kt*32 + quad*8);
      float4 f0 = fp[0], f1 = fp[1];
      float fv[8] = {f0.x,f0.y,f0.z,f0.w,f1.x,f1.y,f1.z,f1.w};
      bf16x8 v;
      #pragma unroll
      for (int j = 0; j < 8; ++j) v[j] = (__bf16)fv[j];
      Af[kt] = v;
    }
    float cw[4], dxw[4], dyw[4], dzw[4];
    #pragma unroll
    for (int r = 0; r < 4; ++r) {
      int row = row0 + quad*4 + r;
      cw[r] = cnt[row]; dxw[r] = DXa[row]; dyw[r] = DYa[row]; dzw[r] = DZa[row];
    }
    #pragma unroll
    for (int nt = 0; nt < 4; ++nt) {
      f32x4 a = {0.f, 0.f, 0.f, 0.f};
      a = __builtin_amdgcn_mfma_f32_16x16x32_bf16(Af[0], Bf[0][nt], a, 0, 0, 0);
      a = __builtin_amdgcn_mfma_f32_16x16x32_bf16(Af[1], Bf[1][nt], a, 0, 0, 0);
      #pragma unroll
      for (int r = 0; r < 4; ++r) {
        float v = a[r];
        g[(size_t)(row0 + quad*4 + r)*CC1 + nt*16 + col] = v;
        float cv = cw[r]*v;
        a1[nt] += cv; a2[nt] = fmaf(cv, v, a2[nt]);
        a3[nt] = fmaf(dxw[r], v, a3[nt]);
        a4[nt] = fmaf(dyw[r], v, a4[nt]);
        a5[nt] = fmaf(dzw[r], v, a5[nt]);
      }
    }
  }
  #pragma unroll
  for (int nt = 0; nt < 4; ++nt) {
    float v1=a1[nt], v2=a2[nt], v3=a3[nt], v4=a4[nt], v5=a5[nt];
    v1 += __shfl_xor(v1,16,64); v1 += __shfl_xor(v1,32,64);
    v2 += __shfl_xor(v2,16,64); v2 += __shfl_xor(v2,32,64);
    v3 += __shfl_xor(v3,16,64); v3 += __shfl_xor(v3,32,64);
    v4 += __shfl_xor(v4,16,64); v4 += __shfl_xor(v4,32,64);
    v5 += __shfl_xor(v5,16,64); v5 += __shfl_xor(v5,32,64);
    if (quad == 0) {
      int ch = nt*16 + col;
      lds_add(&red[ch], v1);
      lds_add(&red[64+ch], v2);
      lds_add(&red[128+ch], v3);
      lds_add(&red[192+ch], v4);
      lds_add(&red[256+ch], v5);
    }
  }
  __syncthreads();
  for (int i = threadIdx.x; i < 320; i += 256) unsafeAtomicAdd(&A[i], red[i]);
}

// ---------------- KS: assemble stats1 -> sc1, sh1, W1s ----------------
__global__ __launch_bounds__(256) void kS_fold(
    const float* __restrict__ W1, const float* __restrict__ gamma1,
    const float* __restrict__ beta1, const float* __restrict__ A,
    const float* __restrict__ mom,
    float* __restrict__ sc1, float* __restrict__ sh1, float* __restrict__ W1s)
{
  int c = threadIdx.x;
  if (c >= CC1) return;
  float wx = W1[c], wy = W1[CC1+c], wz = W1[2*CC1+c];
  float A1 = A[c], A2 = A[64+c], A3x = A[128+c], A3y = A[192+c], A3z = A[256+c];
  float sum1 = A1 + wx*mom[0] + wy*mom[1] + wz*mom[2];
  float ss = A2 + 2.f*(wx*A3x + wy*A3y + wz*A3z)
           + wx*wx*mom[3] + wy*wy*mom[4] + wz*wz*mom[5]
           + 2.f*(wx*wy*mom[6] + wx*wz*mom[7] + wy*wz*mom[8]);
  const float invN = 1.0f / (float)TOTROWS;
  float mean = sum1 * invN;
  float var  = ss * invN - mean*mean;
  float sc = rsqrtf(var + 1e-5f) * gamma1[c];
  float sh = beta1[c] - mean * sc;
  sc1[c] = sc; sh1[c] = sh;
  W1s[c] = wx*sc; W1s[64+c] = wy*sc; W1s[128+c] = wz*sc;
}

// ---------------- KD: MFMA main pass (BN1 inline) ----------------
// 1024 blocks -> 4096 waves x 4 sites. Per site A1(32x64 bf16) @ W2(64x128).
// a = relu(g*sc + dx*wxs + dy*wys + dz*wzs + sh).
__global__ __launch_bounds__(256, 4) void kD_mfma(
    const float* __restrict__ pos, const int* __restrict__ idx,
    const float* __restrict__ g, const float* __restrict__ sc1,
    const float* __restrict__ sh1, const float* __restrict__ W1s,
    const float* __restrict__ W2,
    float* __restrict__ stats2, float* __restrict__ out_nf)
{
  __shared__ float red2[256];
  red2[threadIdx.x] = 0.f;
  __syncthreads();
  const int lane = threadIdx.x & 63;
  const int quad = lane >> 4;
  const int col  = lane & 15;
  const int gw = (blockIdx.x*256 + threadIdx.x) >> 6;

  bf16x8 Bf[2][8];
  #pragma unroll
  for (int kt = 0; kt < 2; ++kt)
    #pragma unroll
    for (int nt = 0; nt < 8; ++nt) {
      bf16x8 v;
      #pragma unroll
      for (int j = 0; j < 8; ++j)
        v[j] = (__bf16)W2[(kt*32 + quad*8 + j)*CC2 + nt*16 + col];
      Bf[kt][nt] = v;
    }
  float wxs[2][8], wys[2][8], wzs[2][8], scj[2][8], shj[2][8];
  #pragma unroll
  for (int kt = 0; kt < 2; ++kt)
    #pragma unroll
    for (int j = 0; j < 8; ++j) {
      int c = kt*32 + quad*8 + j;
      wxs[kt][j] = W1s[c]; wys[kt][j] = W1s[64+c]; wzs[kt][j] = W1s[128+c];
      scj[kt][j] = sc1[c]; shj[kt][j] = sh1[c];
    }
  float ssum[8], ssq[8];
  #pragma unroll
  for (int nt = 0; nt < 8; ++nt) { ssum[nt] = 0.f; ssq[nt] = 0.f; }

  for (int si = 0; si < 4; ++si) {
    const int site = gw*4 + si;
    const int b = site >> 11;
    const float* pc = pos + (size_t)site*3;
    const float cx = pc[0], cy = pc[1], cz = pc[2];
    int mm[2]; float dx[2], dy[2], dz[2];
    #pragma unroll
    for (int mt = 0; mt < 2; ++mt) {
      mm[mt] = idx[site*KK + mt*16 + col];
      const float* pm = pos + ((size_t)b*NN + mm[mt])*3;
      dx[mt] = pm[0]-cx; dy[mt] = pm[1]-cy; dz[mt] = pm[2]-cz;
    }
    bf16x8 Af[2][2];
    #pragma unroll
    for (int mt = 0; mt < 2; ++mt)
      #pragma unroll
      for (int kt = 0; kt < 2; ++kt) {
        const float4* gp =
          (const float4*)(g + (((size_t)b*NN + mm[mt])*CC1 + kt*32 + quad*8));
        float4 g0 = gp[0], g1 = gp[1];
        float hv[8] = {g0.x,g0.y,g0.z,g0.w,g1.x,g1.y,g1.z,g1.w};
        bf16x8 v;
        #pragma unroll
        for (int j = 0; j < 8; ++j) {
          float t = fmaf(dz[mt], wzs[kt][j],
                    fmaf(dy[mt], wys[kt][j],
                    fmaf(dx[mt], wxs[kt][j], shj[kt][j])));
          float h = fmaf(hv[j], scj[kt][j], t);
          v[j] = (__bf16)fmaxf(h, 0.f);
        }
        Af[mt][kt] = v;
      }
    float mx[8];
    #pragma unroll
    for (int nt = 0; nt < 8; ++nt) mx[nt] = -3.0e38f;
    #pragma unroll
    for (int mt = 0; mt < 2; ++mt) {
      f32x4 acc[8];
      #pragma unroll
      for (int nt = 0; nt < 8; ++nt) {
        f32x4 a = {0.f, 0.f, 0.f, 0.f};
        a = __builtin_amdgcn_mfma_f32_16x16x32_bf16(Af[mt][0], Bf[0][nt], a, 0, 0, 0);
        a = __builtin_amdgcn_mfma_f32_16x16x32_bf16(Af[mt][1], Bf[1][nt], a, 0, 0, 0);
        acc[nt] = a;
      }
      #pragma unroll
      for (int nt = 0; nt < 8; ++nt)
        #pragma unroll
        for (int r = 0; r < 4; ++r) {
          float v = acc[nt][r];
          ssum[nt] += v; ssq[nt] = fmaf(v, v, ssq[nt]);
          mx[nt] = fmaxf(mx[nt], v);
        }
    }
    #pragma unroll
    for (int nt = 0; nt < 8; ++nt) {
      float m = mx[nt];
      m = fmaxf(m, __shfl_xor(m, 16, 64));
      m = fmaxf(m, __shfl_xor(m, 32, 64));
      if ((nt & 3) == quad)
        out_nf[(size_t)site*CC2 + nt*16 + col] = m;   // pre-BN pooled
    }
  }
  #pragma unroll
  for (int nt = 0; nt < 8; ++nt) {
    float s = ssum[nt];
    s += __shfl_xor(s, 16, 64); s += __shfl_xor(s, 32, 64);
    float q = ssq[nt];
    q += __shfl_xor(q, 16, 64); q += __shfl_xor(q, 32, 64);
    if (lane < 16) {
      lds_add(&red2[nt*16 + col], s);
      lds_add(&red2[128 + nt*16 + col], q);
    }
  }
  __syncthreads();
  unsafeAtomicAdd(&stats2[threadIdx.x], red2[threadIdx.x]);
}

// ---------------- K45: position copy + bn2/relu in place ----------------
// blocks [0,192): copy position (49152 elems); blocks [192,8384): bn2.
__global__ __launch_bounds__(256) void k45_epi(const float* __restrict__ pos,
                                               const float* __restrict__ g2,
                                               const float* __restrict__ be2,
                                               const float* __restrict__ stats2,
                                               float* __restrict__ out)
{
  int i = blockIdx.x*256 + threadIdx.x;
  if (blockIdx.x < 192) { out[i] = pos[i]; return; }
  int j = i - 192*256;
  int c = j & (CC2-1);
  const float invc = 1.0f / (float)TOTROWS;
  float mean = stats2[c] * invc;
  float var  = stats2[128 + c] * invc - mean*mean;
  float sc = rsqrtf(var + 1e-5f) * g2[c];
  float sh = be2[c] - mean * sc;
  float* out_nf = out + (size_t)BB*NN*3;
  float x = out_nf[j];
  out_nf[j] = fmaxf(fmaf(x, sc, sh), 0.f);
}

extern "C" void kernel_launch(void* const* d_in, const int* in_sizes, int n_in,
                              void* d_out, int out_size, void* d_ws, size_t ws_size,
                              hipStream_t stream) {
  const float* pos  = (const float*)d_in[0];
  const float* feat = (const float*)d_in[1];
  const float* W1   = (const float*)d_in[2];
  const float* g1   = (const float*)d_in[3];
  const float* be1  = (const float*)d_in[4];
  const float* W2   = (const float*)d_in[5];
  const float* g2   = (const float*)d_in[6];
  const float* be2  = (const float*)d_in[7];
  float* out = (float*)d_out;
  float* out_nf = out + (size_t)BB*NN*3;

  char* w = (char*)d_ws;
  int*   idx    = (int*)w;                   // 2 MB
  float* cnt    = (float*)(w + 0x200000);    // 16384
  float* DXa    = cnt + SITES;
  float* DYa    = DXa + SITES;
  float* DZa    = DYa + SITES;
  float* A      = DZa + SITES;               // 320
  float* mom    = A + 320;                   // 9 (pad to 16)
  float* stats2 = mom + 16;                  // 256
  float* sc1    = stats2 + 256;              // 64
  float* sh1    = sc1 + 64;                  // 64
  float* W1s    = sh1 + 64;                  // 192
  float* g      = (float*)(w + 0x200000 + 0x50000);  // 4 MB

  hipMemsetAsync(cnt, 0, (4*SITES + 320 + 16 + 256)*sizeof(float), stream);
  k1_ball   <<<512, 256, 0, stream>>>(pos, idx);
  kP_scatter<<<256, 512, 0, stream>>>(pos, idx, cnt, DXa, DYa, DZa, mom);
  kB_g      <<<128, 256, 0, stream>>>(feat, W1, cnt, DXa, DYa, DZa, g, A);
  kS_fold   <<<1, 256, 0, stream>>>(W1, g1, be1, A, mom, sc1, sh1, W1s);
  kD_mfma   <<<1024, 256, 0, stream>>>(pos, idx, g, sc1, sh1, W1s, W2,
                                       stats2, out_nf);
  k45_epi   <<<192 + (SITES*CC2)/256, 256, 0, stream>>>(pos, g2, be2, stats2, out);
}

// Round 10
// 312.474 us; speedup vs baseline: 1.8087x; 1.8087x over previous
//
#include <hip/hip_runtime.h>
#include <hip/hip_bf16.h>

// LocalAggregation: B=8, N=2048, K=32, D=64, C1=64, C2=128, R=0.15, EPS=1e-5
// f32 storage, bf16-ified values.
// Factored stats1 (validated R7/R8):
//   h1[row,c] = g[m,c] + dx*wx[c]+dy*wy[c]+dz*wz[c],  g = feat @ W1[3:]
//   sum1[c]   = SUM_m cnt[m] g[m,c] + wx M1x + wy M1y + wz M1z
//   sumsq1[c] = SUM_m cnt g^2 + 2(wx A3x + wy A3y + wz A3z) + quadratic moments
// R10: kP v3 — padding entries (k>0 && ip[k]==ip[0]) aggregated per-thread
//   into ONE atomic (kills the same-address LDS storm that cost 88-251 us);
//   thread = (site, 8-k group), plain atomicAdd on LDS (collision-free now).
//   kD reverted byte-identical to R8 ((256,2), VGPR 112 — R9's (256,4)
//   forced a 64-VGPR cap -> 676 MB scratch spill, 257 us).
// gamma2>0 => max-pool commutes with bn2+relu (k45).

#define BB 8
#define NN 2048
#define KK 32
#define DD 64
#define CC1 64
#define CC2 128
#define TOTROWS (BB*NN*KK) // 524288
#define SITES (BB*NN)      // 16384

typedef __bf16 bf16x8 __attribute__((ext_vector_type(8)));
typedef float  f32x4  __attribute__((ext_vector_type(4)));

__device__ __forceinline__ void lds_add(float* p, float v) {
  __hip_atomic_fetch_add(p, v, __ATOMIC_RELAXED, __HIP_MEMORY_SCOPE_WORKGROUP);
}

// ---------------- K1: ball query, ballot compaction ----------------
// 512 blocks x 256 thr; block = (batch, 32-query group), wave = 8 queries.
__global__ __launch_bounds__(256) void k1_ball(const float* __restrict__ pos,
                                               int* __restrict__ idx)
{
  __shared__ float4 P[NN];  // 32 KB: x,y,z,S
  const int b = blockIdx.x >> 6;
  const int qbase = (blockIdx.x & 63) * 32;
  for (int i = threadIdx.x; i < NN; i += 256) {
    const float* p = pos + ((size_t)b*NN + i)*3;
    float x = p[0], y = p[1], z = p[2];
    float s = __fadd_rn(__fadd_rn(__fmul_rn(x,x), __fmul_rn(y,y)), __fmul_rn(z,z));
    P[i] = make_float4(x, y, z, s);
  }
  __syncthreads();
  const int wave = threadIdx.x >> 6, lane = threadIdx.x & 63;
  const float R2 = (float)(0.15 * 0.15);
  const unsigned long long lt = (lane == 63) ? 0x7fffffffffffffffull
                                             : ((1ull << lane) - 1ull);
  for (int qi = wave; qi < 32; qi += 4) {
    const int q = qbase + qi;
    const float4 Q = P[q];
    int* ip = idx + ((size_t)b*NN + q)*KK;
    int cnt = 0, first = -1;
    for (int step = 0; step < 32; ++step) {
      float4 p = P[step*64 + lane];
      float d = __fmul_rn(Q.x, p.x);
      d = fmaf(Q.y, p.y, d);
      d = fmaf(Q.z, p.z, d);
      float sq = __fsub_rn(__fadd_rn(Q.w, p.w), __fmul_rn(2.0f, d));
      bool in = !(sq > R2);
      unsigned long long mask = __ballot(in);
      if (first < 0 && mask) first = step*64 + (int)__builtin_ctzll(mask);
      int dst = cnt + (int)__popcll(mask & lt);
      if (in && dst < KK) ip[dst] = step*64 + lane;
      cnt += (int)__popcll(mask);
      if (cnt >= KK) break;
    }
    if (lane >= cnt && lane < KK) ip[lane] = first;  // cnt>=1 (self in ball)
  }
}

// ---------------- KP v3: per-m scatter + global moments ----------------
// 256 blocks x 256 thr; block = (batch, 64-site slice); thread = (site, k/8).
// Padding (k>0 && m==ip0) aggregated into one atomic per thread — no storms.
__global__ __launch_bounds__(256) void kP_scatter(
    const float* __restrict__ pos, const int* __restrict__ idx,
    float* __restrict__ cnt, float* __restrict__ DXa,
    float* __restrict__ DYa, float* __restrict__ DZa,
    float* __restrict__ mom)
{
  __shared__ float Sc[NN], Sx[NN], Sy[NN], Sz[NN];  // 32 KB
  const int b = blockIdx.x >> 5;
  const int slice = blockIdx.x & 31;   // 64 sites
  for (int i = threadIdx.x; i < NN; i += 256) {
    Sc[i] = 0.f; Sx[i] = 0.f; Sy[i] = 0.f; Sz[i] = 0.f;
  }
  __syncthreads();
  const float* pb = pos + (size_t)b*NN*3;
  const int sl = threadIdx.x >> 2;     // site-local 0..63
  const int kg = threadIdx.x & 3;      // k-group: 8 k's each
  const int site = slice*64 + sl;      // site within batch
  const int* ip = idx + ((size_t)(b*NN + site))*KK;
  const int ip0 = ip[0];
  const float cx = pb[site*3], cy = pb[site*3+1], cz = pb[site*3+2];
  float m1x=0.f,m1y=0.f,m1z=0.f,mxx=0.f,myy=0.f,mzz=0.f,mxy=0.f,mxz=0.f,myz=0.f;
  float wt = 0.f;
  #pragma unroll
  for (int j = 0; j < 8; ++j) {
    const int k = kg*8 + j;
    const int m = ip[k];
    float dx = pb[m*3  ] - cx;
    float dy = pb[m*3+1] - cy;
    float dz = pb[m*3+2] - cz;
    if (k > 0 && m == ip0) {
      wt += 1.f;                        // padding: aggregate
    } else {
      atomicAdd(&Sc[m], 1.0f);          // real: collision-free random m
      atomicAdd(&Sx[m], dx);
      atomicAdd(&Sy[m], dy);
      atomicAdd(&Sz[m], dz);
    }
    m1x += dx; m1y += dy; m1z += dz;    // moments include padding (m==ip0)
    mxx = fmaf(dx,dx,mxx); myy = fmaf(dy,dy,myy); mzz = fmaf(dz,dz,mzz);
    mxy = fmaf(dx,dy,mxy); mxz = fmaf(dx,dz,mxz); myz = fmaf(dy,dz,myz);
  }
  if (wt > 0.f) {
    float dx0 = pb[ip0*3  ] - cx;
    float dy0 = pb[ip0*3+1] - cy;
    float dz0 = pb[ip0*3+2] - cz;
    atomicAdd(&Sc[ip0], wt);
    atomicAdd(&Sx[ip0], wt*dx0);
    atomicAdd(&Sy[ip0], wt*dy0);
    atomicAdd(&Sz[ip0], wt*dz0);
  }
  __syncthreads();
  for (int i = threadIdx.x; i < NN; i += 256) {
    unsafeAtomicAdd(&cnt[b*NN + i], Sc[i]);
    unsafeAtomicAdd(&DXa[b*NN + i], Sx[i]);
    unsafeAtomicAdd(&DYa[b*NN + i], Sy[i]);
    unsafeAtomicAdd(&DZa[b*NN + i], Sz[i]);
  }
  const int lane = threadIdx.x & 63;
  float vals[9] = {m1x,m1y,m1z,mxx,myy,mzz,mxy,mxz,myz};
  #pragma unroll
  for (int i = 0; i < 9; ++i) {
    float v = vals[i];
    #pragma unroll
    for (int s = 1; s < 64; s <<= 1) v += __shfl_xor(v, s, 64);
    if (lane == 0) unsafeAtomicAdd(&mom[i], v);
  }
}

// ---------------- KB: g = feat @ W1[3:] via MFMA, fused A-sums ----------------
// 128 blocks x 256 thr -> 512 waves x 2 M-tiles (16 rows each).
// A layout: [0:64) Sum cnt*g, [64:128) Sum cnt*g^2, [128:192) Sum g*DX,
//           [192:256) Sum g*DY, [256:320) Sum g*DZ
__global__ __launch_bounds__(256) void kB_g(const float* __restrict__ feat,
                                            const float* __restrict__ W1,
                                            const float* __restrict__ cnt,
                                            const float* __restrict__ DXa,
                                            const float* __restrict__ DYa,
                                            const float* __restrict__ DZa,
                                            float* __restrict__ g,
                                            float* __restrict__ A)
{
  __shared__ float red[320];
  for (int i = threadIdx.x; i < 320; i += 256) red[i] = 0.f;
  __syncthreads();
  const int lane = threadIdx.x & 63;
  const int quad = lane >> 4;
  const int col  = lane & 15;
  const int gw = (blockIdx.x*256 + threadIdx.x) >> 6;   // 0..511

  bf16x8 Bf[2][4];
  #pragma unroll
  for (int kt = 0; kt < 2; ++kt)
    #pragma unroll
    for (int nt = 0; nt < 4; ++nt) {
      bf16x8 v;
      #pragma unroll
      for (int j = 0; j < 8; ++j)
        v[j] = (__bf16)W1[(3 + kt*32 + quad*8 + j)*CC1 + nt*16 + col];
      Bf[kt][nt] = v;
    }
  float a1[4], a2[4], a3[4], a4[4], a5[4];
  #pragma unroll
  for (int nt = 0; nt < 4; ++nt) { a1[nt]=0.f; a2[nt]=0.f; a3[nt]=0.f; a4[nt]=0.f; a5[nt]=0.f; }

  for (int t = 0; t < 2; ++t) {
    const int row0 = (gw*2 + t) * 16;
    bf16x8 Af[2];
    #pragma unroll
    for (int kt = 0; kt < 2; ++kt) {
      const float4* fp =
        (const float4*)(feat + (size_t)(row0 + col)*DD + kt*32 + quad*8);
      float4 f0 = fp[0], f1 = fp[1];
      float fv[8] = {f0.x,f0.y,f0.z,f0.w,f1.x,f1.y,f1.z,f1.w};
      bf16x8 v;
      #pragma unroll
      for (int j = 0; j < 8; ++j) v[j] = (__bf16)fv[j];
      Af[kt] = v;
    }
    float cw[4], dxw[4], dyw[4], dzw[4];
    #pragma unroll
    for (int r = 0; r < 4; ++r) {
      int row = row0 + quad*4 + r;
      cw[r] = cnt[row]; dxw[r] = DXa[row]; dyw[r] = DYa[row]; dzw[r] = DZa[row];
    }
    #pragma unroll
    for (int nt = 0; nt < 4; ++nt) {
      f32x4 a = {0.f, 0.f, 0.f, 0.f};
      a = __builtin_amdgcn_mfma_f32_16x16x32_bf16(Af[0], Bf[0][nt], a, 0, 0, 0);
      a = __builtin_amdgcn_mfma_f32_16x16x32_bf16(Af[1], Bf[1][nt], a, 0, 0, 0);
      #pragma unroll
      for (int r = 0; r < 4; ++r) {
        float v = a[r];
        g[(size_t)(row0 + quad*4 + r)*CC1 + nt*16 + col] = v;
        float cv = cw[r]*v;
        a1[nt] += cv; a2[nt] = fmaf(cv, v, a2[nt]);
        a3[nt] = fmaf(dxw[r], v, a3[nt]);
        a4[nt] = fmaf(dyw[r], v, a4[nt]);
        a5[nt] = fmaf(dzw[r], v, a5[nt]);
      }
    }
  }
  #pragma unroll
  for (int nt = 0; nt < 4; ++nt) {
    float v1=a1[nt], v2=a2[nt], v3=a3[nt], v4=a4[nt], v5=a5[nt];
    v1 += __shfl_xor(v1,16,64); v1 += __shfl_xor(v1,32,64);
    v2 += __shfl_xor(v2,16,64); v2 += __shfl_xor(v2,32,64);
    v3 += __shfl_xor(v3,16,64); v3 += __shfl_xor(v3,32,64);
    v4 += __shfl_xor(v4,16,64); v4 += __shfl_xor(v4,32,64);
    v5 += __shfl_xor(v5,16,64); v5 += __shfl_xor(v5,32,64);
    if (quad == 0) {
      int ch = nt*16 + col;
      lds_add(&red[ch], v1);
      lds_add(&red[64+ch], v2);
      lds_add(&red[128+ch], v3);
      lds_add(&red[192+ch], v4);
      lds_add(&red[256+ch], v5);
    }
  }
  __syncthreads();
  for (int i = threadIdx.x; i < 320; i += 256) unsafeAtomicAdd(&A[i], red[i]);
}

// ---------------- KS: assemble stats1 -> sc1, sh1, W1s ----------------
__global__ __launch_bounds__(256) void kS_fold(
    const float* __restrict__ W1, const float* __restrict__ gamma1,
    const float* __restrict__ beta1, const float* __restrict__ A,
    const float* __restrict__ mom,
    float* __restrict__ sc1, float* __restrict__ sh1, float* __restrict__ W1s)
{
  int c = threadIdx.x;
  if (c >= CC1) return;
  float wx = W1[c], wy = W1[CC1+c], wz = W1[2*CC1+c];
  float A1 = A[c], A2 = A[64+c], A3x = A[128+c], A3y = A[192+c], A3z = A[256+c];
  float sum1 = A1 + wx*mom[0] + wy*mom[1] + wz*mom[2];
  float ss = A2 + 2.f*(wx*A3x + wy*A3y + wz*A3z)
           + wx*wx*mom[3] + wy*wy*mom[4] + wz*wz*mom[5]
           + 2.f*(wx*wy*mom[6] + wx*wz*mom[7] + wy*wz*mom[8]);
  const float invN = 1.0f / (float)TOTROWS;
  float mean = sum1 * invN;
  float var  = ss * invN - mean*mean;
  float sc = rsqrtf(var + 1e-5f) * gamma1[c];
  float sh = beta1[c] - mean * sc;
  sc1[c] = sc; sh1[c] = sh;
  W1s[c] = wx*sc; W1s[64+c] = wy*sc; W1s[128+c] = wz*sc;
}

// ---------------- KD: MFMA main pass (BN1 inline) — R8 version ----------------
// 1024 blocks -> 4096 waves x 4 sites. Per site A1(32x64 bf16) @ W2(64x128).
// a = relu(g*sc + dx*wxs + dy*wys + dz*wzs + sh).
__global__ __launch_bounds__(256, 2) void kD_mfma(
    const float* __restrict__ pos, const int* __restrict__ idx,
    const float* __restrict__ g, const float* __restrict__ sc1,
    const float* __restrict__ sh1, const float* __restrict__ W1s,
    const float* __restrict__ W2,
    float* __restrict__ stats2, float* __restrict__ out_nf)
{
  __shared__ float red2[256];
  red2[threadIdx.x] = 0.f;
  __syncthreads();
  const int lane = threadIdx.x & 63;
  const int quad = lane >> 4;
  const int col  = lane & 15;
  const int gw = (blockIdx.x*256 + threadIdx.x) >> 6;

  bf16x8 Bf[2][8];
  #pragma unroll
  for (int kt = 0; kt < 2; ++kt)
    #pragma unroll
    for (int nt = 0; nt < 8; ++nt) {
      bf16x8 v;
      #pragma unroll
      for (int j = 0; j < 8; ++j)
        v[j] = (__bf16)W2[(kt*32 + quad*8 + j)*CC2 + nt*16 + col];
      Bf[kt][nt] = v;
    }
  float wxs[2][8], wys[2][8], wzs[2][8], scj[2][8], shj[2][8];
  #pragma unroll
  for (int kt = 0; kt < 2; ++kt)
    #pragma unroll
    for (int j = 0; j < 8; ++j) {
      int c = kt*32 + quad*8 + j;
      wxs[kt][j] = W1s[c]; wys[kt][j] = W1s[64+c]; wzs[kt][j] = W1s[128+c];
      scj[kt][j] = sc1[c]; shj[kt][j] = sh1[c];
    }
  float ssum[8], ssq[8];
  #pragma unroll
  for (int nt = 0; nt < 8; ++nt) { ssum[nt] = 0.f; ssq[nt] = 0.f; }

  for (int si = 0; si < 4; ++si) {
    const int site = gw*4 + si;
    const int b = site >> 11;
    const float* pc = pos + (size_t)site*3;
    const float cx = pc[0], cy = pc[1], cz = pc[2];
    int mm[2]; float dx[2], dy[2], dz[2];
    #pragma unroll
    for (int mt = 0; mt < 2; ++mt) {
      mm[mt] = idx[site*KK + mt*16 + col];
      const float* pm = pos + ((size_t)b*NN + mm[mt])*3;
      dx[mt] = pm[0]-cx; dy[mt] = pm[1]-cy; dz[mt] = pm[2]-cz;
    }
    bf16x8 Af[2][2];
    #pragma unroll
    for (int mt = 0; mt < 2; ++mt)
      #pragma unroll
      for (int kt = 0; kt < 2; ++kt) {
        const float4* gp =
          (const float4*)(g + (((size_t)b*NN + mm[mt])*CC1 + kt*32 + quad*8));
        float4 g0 = gp[0], g1 = gp[1];
        float hv[8] = {g0.x,g0.y,g0.z,g0.w,g1.x,g1.y,g1.z,g1.w};
        bf16x8 v;
        #pragma unroll
        for (int j = 0; j < 8; ++j) {
          float t = fmaf(dz[mt], wzs[kt][j],
                    fmaf(dy[mt], wys[kt][j],
                    fmaf(dx[mt], wxs[kt][j], shj[kt][j])));
          float h = fmaf(hv[j], scj[kt][j], t);
          v[j] = (__bf16)fmaxf(h, 0.f);
        }
        Af[mt][kt] = v;
      }
    float mx[8];
    #pragma unroll
    for (int nt = 0; nt < 8; ++nt) mx[nt] = -3.0e38f;
    #pragma unroll
    for (int mt = 0; mt < 2; ++mt) {
      f32x4 acc[8];
      #pragma unroll
      for (int nt = 0; nt < 8; ++nt) {
        f32x4 a = {0.f, 0.f, 0.f, 0.f};
        a = __builtin_amdgcn_mfma_f32_16x16x32_bf16(Af[mt][0], Bf[0][nt], a, 0, 0, 0);
        a = __builtin_amdgcn_mfma_f32_16x16x32_bf16(Af[mt][1], Bf[1][nt], a, 0, 0, 0);
        acc[nt] = a;
      }
      #pragma unroll
      for (int nt = 0; nt < 8; ++nt)
        #pragma unroll
        for (int r = 0; r < 4; ++r) {
          float v = acc[nt][r];
          ssum[nt] += v; ssq[nt] = fmaf(v, v, ssq[nt]);
          mx[nt] = fmaxf(mx[nt], v);
        }
    }
    #pragma unroll
    for (int nt = 0; nt < 8; ++nt) {
      float m = mx[nt];
      m = fmaxf(m, __shfl_xor(m, 16, 64));
      m = fmaxf(m, __shfl_xor(m, 32, 64));
      if ((nt & 3) == quad)
        out_nf[(size_t)site*CC2 + nt*16 + col] = m;   // pre-BN pooled
    }
  }
  #pragma unroll
  for (int nt = 0; nt < 8; ++nt) {
    float s = ssum[nt];
    s += __shfl_xor(s, 16, 64); s += __shfl_xor(s, 32, 64);
    float q = ssq[nt];
    q += __shfl_xor(q, 16, 64); q += __shfl_xor(q, 32, 64);
    if (lane < 16) {
      atomicAdd(&red2[nt*16 + col], s);
      atomicAdd(&red2[128 + nt*16 + col], q);
    }
  }
  __syncthreads();
  unsafeAtomicAdd(&stats2[threadIdx.x], red2[threadIdx.x]);
}

// ---------------- K45: position copy + bn2/relu in place ----------------
// blocks [0,192): copy position (49152 elems); blocks [192,8384): bn2.
__global__ __launch_bounds__(256) void k45_epi(const float* __restrict__ pos,
                                               const float* __restrict__ g2,
                                               const float* __restrict__ be2,
                                               const float* __restrict__ stats2,
                                               float* __restrict__ out)
{
  int i = blockIdx.x*256 + threadIdx.x;
  if (blockIdx.x < 192) { out[i] = pos[i]; return; }
  int j = i - 192*256;
  int c = j & (CC2-1);
  const float invc = 1.0f / (float)TOTROWS;
  float mean = stats2[c] * invc;
  float var  = stats2[128 + c] * invc - mean*mean;
  float sc = rsqrtf(var + 1e-5f) * g2[c];
  float sh = be2[c] - mean * sc;
  float* out_nf = out + (size_t)BB*NN*3;
  float x = out_nf[j];
  out_nf[j] = fmaxf(fmaf(x, sc, sh), 0.f);
}

extern "C" void kernel_launch(void* const* d_in, const int* in_sizes, int n_in,
                              void* d_out, int out_size, void* d_ws, size_t ws_size,
                              hipStream_t stream) {
  const float* pos  = (const float*)d_in[0];
  const float* feat = (const float*)d_in[1];
  const float* W1   = (const float*)d_in[2];
  const float* g1   = (const float*)d_in[3];
  const float* be1  = (const float*)d_in[4];
  const float* W2   = (const float*)d_in[5];
  const float* g2   = (const float*)d_in[6];
  const float* be2  = (const float*)d_in[7];
  float* out = (float*)d_out;
  float* out_nf = out + (size_t)BB*NN*3;

  char* w = (char*)d_ws;
  int*   idx    = (int*)w;                   // 2 MB
  float* cnt    = (float*)(w + 0x200000);    // 16384
  float* DXa    = cnt + SITES;
  float* DYa    = DXa + SITES;
  float* DZa    = DYa + SITES;
  float* A      = DZa + SITES;               // 320
  float* mom    = A + 320;                   // 9 (pad to 16)
  float* stats2 = mom + 16;                  // 256
  float* sc1    = stats2 + 256;              // 64
  float* sh1    = sc1 + 64;                  // 64
  float* W1s    = sh1 + 64;                  // 192
  float* g      = (float*)(w + 0x200000 + 0x50000);  // 4 MB

  hipMemsetAsync(cnt, 0, (4*SITES + 320 + 16 + 256)*sizeof(float), stream);
  k1_ball   <<<512, 256, 0, stream>>>(pos, idx);
  kP_scatter<<<256, 256, 0, stream>>>(pos, idx, cnt, DXa, DYa, DZa, mom);
  kB_g      <<<128, 256, 0, stream>>>(feat, W1, cnt, DXa, DYa, DZa, g, A);
  kS_fold   <<<1, 256, 0, stream>>>(W1, g1, be1, A, mom, sc1, sh1, W1s);
  kD_mfma   <<<1024, 256, 0, stream>>>(pos, idx, g, sc1, sh1, W1s, W2,
                                       stats2, out_nf);
  k45_epi   <<<192 + (SITES*CC2)/256, 256, 0, stream>>>(pos, g2, be2, stats2, out);
}

// Round 11
// 251.921 us; speedup vs baseline: 2.2434x; 1.2404x over previous
//
#include <hip/hip_runtime.h>
#include <hip/hip_bf16.h>

// LocalAggregation: B=8, N=2048, K=32, D=64, C1=64, C2=128, R=0.15, EPS=1e-5
// f32 storage, bf16-ified values.
// Factored stats1 (validated R7-R10):
//   h1[row,c] = g[m,c] + dx*wx[c]+dy*wy[c]+dz*wz[c],  g = feat @ W1[3:]
//   sum1[c]   = SUM_m cnt[m] g[m,c] + wx M1x + wy M1y + wz M1z
//   sumsq1[c] = SUM_m cnt g^2 + 2(wx A3x + wy A3y + wz A3z) + quadratic moments
// R11: kP v4 — LDS atomics are INTEGER ONLY (ds_add_u32 counts, ds_add_u64
//   fixed-point 2^-37 for DX/DY/DZ; f32 LDS atomicAdd was a CAS loop: R8-R10
//   all 88-251 us at <0.5% VALU). Flush is plain stores of per-block partials
//   (4 MB); kR_reduce sums 16 partials/batch — zero global atomics on hot path.
//   kD remains the R8 version ((256,2); R9's (256,4) spilled).
// gamma2>0 => max-pool commutes with bn2+relu (k45).

#define BB 8
#define NN 2048
#define KK 32
#define DD 64
#define CC1 64
#define CC2 128
#define TOTROWS (BB*NN*KK) // 524288
#define SITES (BB*NN)      // 16384

typedef __bf16 bf16x8 __attribute__((ext_vector_type(8)));
typedef float  f32x4  __attribute__((ext_vector_type(4)));

__device__ __forceinline__ void lds_add(float* p, float v) {
  __hip_atomic_fetch_add(p, v, __ATOMIC_RELAXED, __HIP_MEMORY_SCOPE_WORKGROUP);
}

// ---------------- K1: ball query, ballot compaction ----------------
// 512 blocks x 256 thr; block = (batch, 32-query group), wave = 8 queries.
__global__ __launch_bounds__(256) void k1_ball(const float* __restrict__ pos,
                                               int* __restrict__ idx)
{
  __shared__ float4 P[NN];  // 32 KB: x,y,z,S
  const int b = blockIdx.x >> 6;
  const int qbase = (blockIdx.x & 63) * 32;
  for (int i = threadIdx.x; i < NN; i += 256) {
    const float* p = pos + ((size_t)b*NN + i)*3;
    float x = p[0], y = p[1], z = p[2];
    float s = __fadd_rn(__fadd_rn(__fmul_rn(x,x), __fmul_rn(y,y)), __fmul_rn(z,z));
    P[i] = make_float4(x, y, z, s);
  }
  __syncthreads();
  const int wave = threadIdx.x >> 6, lane = threadIdx.x & 63;
  const float R2 = (float)(0.15 * 0.15);
  const unsigned long long lt = (lane == 63) ? 0x7fffffffffffffffull
                                             : ((1ull << lane) - 1ull);
  for (int qi = wave; qi < 32; qi += 4) {
    const int q = qbase + qi;
    const float4 Q = P[q];
    int* ip = idx + ((size_t)b*NN + q)*KK;
    int cnt = 0, first = -1;
    for (int step = 0; step < 32; ++step) {
      float4 p = P[step*64 + lane];
      float d = __fmul_rn(Q.x, p.x);
      d = fmaf(Q.y, p.y, d);
      d = fmaf(Q.z, p.z, d);
      float sq = __fsub_rn(__fadd_rn(Q.w, p.w), __fmul_rn(2.0f, d));
      bool in = !(sq > R2);
      unsigned long long mask = __ballot(in);
      if (first < 0 && mask) first = step*64 + (int)__builtin_ctzll(mask);
      int dst = cnt + (int)__popcll(mask & lt);
      if (in && dst < KK) ip[dst] = step*64 + lane;
      cnt += (int)__popcll(mask);
      if (cnt >= KK) break;
    }
    if (lane >= cnt && lane < KK) ip[lane] = first;  // cnt>=1 (self in ball)
  }
}

// ---------------- KP v4: per-m scatter, integer LDS atomics, partial stores ----------------
// 128 blocks x 256 thr; block = (batch, 128-site slice); thread = (site, k/16).
// Padding (k>0 && m==ip0) aggregated into one add per thread.
__global__ __launch_bounds__(256) void kP_scatter(
    const float* __restrict__ pos, const int* __restrict__ idx,
    float* __restrict__ Pc, float* __restrict__ Px,
    float* __restrict__ Py, float* __restrict__ Pz,
    float* __restrict__ mom)
{
  __shared__ unsigned int       Sc[NN];              // 8 KB
  __shared__ unsigned long long Sx[NN], Sy[NN], Sz[NN]; // 48 KB
  const int b = blockIdx.x >> 4;       // 16 slices per batch
  const int slice = blockIdx.x & 15;   // 128 sites each
  for (int i = threadIdx.x; i < NN; i += 256) {
    Sc[i] = 0u; Sx[i] = 0ull; Sy[i] = 0ull; Sz[i] = 0ull;
  }
  __syncthreads();
  const float* pb = pos + (size_t)b*NN*3;
  const int sl = threadIdx.x >> 1;     // site-local 0..127
  const int kg = threadIdx.x & 1;      // k-group: 16 k's each
  const int site = slice*128 + sl;
  const int* ip = idx + ((size_t)(b*NN + site))*KK;
  const int ip0 = ip[0];
  const float cx = pb[site*3], cy = pb[site*3+1], cz = pb[site*3+2];
  const float FS = 137438953472.0f;    // 2^37
  float m1x=0.f,m1y=0.f,m1z=0.f,mxx=0.f,myy=0.f,mzz=0.f,mxy=0.f,mxz=0.f,myz=0.f;
  int wt = 0;
  #pragma unroll
  for (int j = 0; j < 16; ++j) {
    const int k = kg*16 + j;
    const int m = ip[k];
    float dx = pb[m*3  ] - cx;
    float dy = pb[m*3+1] - cy;
    float dz = pb[m*3+2] - cz;
    if (k > 0 && m == ip0) {
      ++wt;                             // padding: aggregate
    } else {
      atomicAdd(&Sc[m], 1u);            // ds_add_u32
      atomicAdd(&Sx[m], (unsigned long long)__float2ll_rn(dx*FS));
      atomicAdd(&Sy[m], (unsigned long long)__float2ll_rn(dy*FS));
      atomicAdd(&Sz[m], (unsigned long long)__float2ll_rn(dz*FS));
    }
    m1x += dx; m1y += dy; m1z += dz;    // moments include padding rows
    mxx = fmaf(dx,dx,mxx); myy = fmaf(dy,dy,myy); mzz = fmaf(dz,dz,mzz);
    mxy = fmaf(dx,dy,mxy); mxz = fmaf(dx,dz,mxz); myz = fmaf(dy,dz,myz);
  }
  if (wt > 0) {
    float dx0 = pb[ip0*3  ] - cx;
    float dy0 = pb[ip0*3+1] - cy;
    float dz0 = pb[ip0*3+2] - cz;
    atomicAdd(&Sc[ip0], (unsigned int)wt);
    atomicAdd(&Sx[ip0], (unsigned long long)((long long)wt*__float2ll_rn(dx0*FS)));
    atomicAdd(&Sy[ip0], (unsigned long long)((long long)wt*__float2ll_rn(dy0*FS)));
    atomicAdd(&Sz[ip0], (unsigned long long)((long long)wt*__float2ll_rn(dz0*FS)));
  }
  __syncthreads();
  const float IS = 7.2759576141834259e-12f;  // 2^-37
  float* pc = Pc + (size_t)blockIdx.x*NN;
  float* px = Px + (size_t)blockIdx.x*NN;
  float* py = Py + (size_t)blockIdx.x*NN;
  float* pz = Pz + (size_t)blockIdx.x*NN;
  for (int i = threadIdx.x; i < NN; i += 256) {
    pc[i] = (float)Sc[i];
    px[i] = (float)(long long)Sx[i] * IS;
    py[i] = (float)(long long)Sy[i] * IS;
    pz[i] = (float)(long long)Sz[i] * IS;
  }
  const int lane = threadIdx.x & 63;
  float vals[9] = {m1x,m1y,m1z,mxx,myy,mzz,mxy,mxz,myz};
  #pragma unroll
  for (int i = 0; i < 9; ++i) {
    float v = vals[i];
    #pragma unroll
    for (int s = 1; s < 64; s <<= 1) v += __shfl_xor(v, s, 64);
    if (lane == 0) unsafeAtomicAdd(&mom[i], v);
  }
}

// ---------------- KR: reduce 16 partials/batch -> cnt/DXa/DYa/DZa ----------------
// 256 blocks x 256 thr; i in [0,65536): a = array, j = b*2048+m.
__global__ __launch_bounds__(256) void kR_reduce(
    const float* __restrict__ Pc, const float* __restrict__ Px,
    const float* __restrict__ Py, const float* __restrict__ Pz,
    float* __restrict__ cnt, float* __restrict__ DXa,
    float* __restrict__ DYa, float* __restrict__ DZa)
{
  int i = blockIdx.x*256 + threadIdx.x;
  int a = i >> 14;              // 0..3
  int j = i & 16383;            // b*2048 + m
  int b = j >> 11, m = j & (NN-1);
  const float* P = (a == 0) ? Pc : (a == 1) ? Px : (a == 2) ? Py : Pz;
  float s = 0.f;
  #pragma unroll
  for (int sl = 0; sl < 16; ++sl) s += P[(size_t)(b*16 + sl)*NN + m];
  float* O = (a == 0) ? cnt : (a == 1) ? DXa : (a == 2) ? DYa : DZa;
  O[j] = s;
}

// ---------------- KB: g = feat @ W1[3:] via MFMA, fused A-sums ----------------
// 128 blocks x 256 thr -> 512 waves x 2 M-tiles (16 rows each).
// A layout: [0:64) Sum cnt*g, [64:128) Sum cnt*g^2, [128:192) Sum g*DX,
//           [192:256) Sum g*DY, [256:320) Sum g*DZ
__global__ __launch_bounds__(256) void kB_g(const float* __restrict__ feat,
                                            const float* __restrict__ W1,
                                            const float* __restrict__ cnt,
                                            const float* __restrict__ DXa,
                                            const float* __restrict__ DYa,
                                            const float* __restrict__ DZa,
                                            float* __restrict__ g,
                                            float* __restrict__ A)
{
  __shared__ float red[320];
  for (int i = threadIdx.x; i < 320; i += 256) red[i] = 0.f;
  __syncthreads();
  const int lane = threadIdx.x & 63;
  const int quad = lane >> 4;
  const int col  = lane & 15;
  const int gw = (blockIdx.x*256 + threadIdx.x) >> 6;   // 0..511

  bf16x8 Bf[2][4];
  #pragma unroll
  for (int kt = 0; kt < 2; ++kt)
    #pragma unroll
    for (int nt = 0; nt < 4; ++nt) {
      bf16x8 v;
      #pragma unroll
      for (int j = 0; j < 8; ++j)
        v[j] = (__bf16)W1[(3 + kt*32 + quad*8 + j)*CC1 + nt*16 + col];
      Bf[kt][nt] = v;
    }
  float a1[4], a2[4], a3[4], a4[4], a5[4];
  #pragma unroll
  for (int nt = 0; nt < 4; ++nt) { a1[nt]=0.f; a2[nt]=0.f; a3[nt]=0.f; a4[nt]=0.f; a5[nt]=0.f; }

  for (int t = 0; t < 2; ++t) {
    const int row0 = (gw*2 + t) * 16;
    bf16x8 Af[2];
    #pragma unroll
    for (int kt = 0; kt < 2; ++kt) {
      const float4* fp =
        (const float4*)(feat + (size_t)(row0 + col)*DD + kt*32 + quad*8);
      float4 f0 = fp[0], f1 = fp[1];
      float fv[8] = {f0.x,f0.y,f0.z,f0.w,f1.x,f1.y,f1.z,f1.w};
      bf16x8 v;
      #pragma unroll
      for (int j = 0; j < 8; ++j) v[j] = (__bf16)fv[j];
      Af[kt] = v;
    }
    float cw[4], dxw[4], dyw[4], dzw[4];
    #pragma unroll
    for (int r = 0; r < 4; ++r) {
      int row = row0 + quad*4 + r;
      cw[r] = cnt[row]; dxw[r] = DXa[row]; dyw[r] = DYa[row]; dzw[r] = DZa[row];
    }
    #pragma unroll
    for (int nt = 0; nt < 4; ++nt) {
      f32x4 a = {0.f, 0.f, 0.f, 0.f};
      a = __builtin_amdgcn_mfma_f32_16x16x32_bf16(Af[0], Bf[0][nt], a, 0, 0, 0);
      a = __builtin_amdgcn_mfma_f32_16x16x32_bf16(Af[1], Bf[1][nt], a, 0, 0, 0);
      #pragma unroll
      for (int r = 0; r < 4; ++r) {
        float v = a[r];
        g[(size_t)(row0 + quad*4 + r)*CC1 + nt*16 + col] = v;
        float cv = cw[r]*v;
        a1[nt] += cv; a2[nt] = fmaf(cv, v, a2[nt]);
        a3[nt] = fmaf(dxw[r], v, a3[nt]);
        a4[nt] = fmaf(dyw[r], v, a4[nt]);
        a5[nt] = fmaf(dzw[r], v, a5[nt]);
      }
    }
  }
  #pragma unroll
  for (int nt = 0; nt < 4; ++nt) {
    float v1=a1[nt], v2=a2[nt], v3=a3[nt], v4=a4[nt], v5=a5[nt];
    v1 += __shfl_xor(v1,16,64); v1 += __shfl_xor(v1,32,64);
    v2 += __shfl_xor(v2,16,64); v2 += __shfl_xor(v2,32,64);
    v3 += __shfl_xor(v3,16,64); v3 += __shfl_xor(v3,32,64);
    v4 += __shfl_xor(v4,16,64); v4 += __shfl_xor(v4,32,64);
    v5 += __shfl_xor(v5,16,64); v5 += __shfl_xor(v5,32,64);
    if (quad == 0) {
      int ch = nt*16 + col;
      lds_add(&red[ch], v1);
      lds_add(&red[64+ch], v2);
      lds_add(&red[128+ch], v3);
      lds_add(&red[192+ch], v4);
      lds_add(&red[256+ch], v5);
    }
  }
  __syncthreads();
  for (int i = threadIdx.x; i < 320; i += 256) unsafeAtomicAdd(&A[i], red[i]);
}

// ---------------- KS: assemble stats1 -> sc1, sh1, W1s ----------------
__global__ __launch_bounds__(256) void kS_fold(
    const float* __restrict__ W1, const float* __restrict__ gamma1,
    const float* __restrict__ beta1, const float* __restrict__ A,
    const float* __restrict__ mom,
    float* __restrict__ sc1, float* __restrict__ sh1, float* __restrict__ W1s)
{
  int c = threadIdx.x;
  if (c >= CC1) return;
  float wx = W1[c], wy = W1[CC1+c], wz = W1[2*CC1+c];
  float A1 = A[c], A2 = A[64+c], A3x = A[128+c], A3y = A[192+c], A3z = A[256+c];
  float sum1 = A1 + wx*mom[0] + wy*mom[1] + wz*mom[2];
  float ss = A2 + 2.f*(wx*A3x + wy*A3y + wz*A3z)
           + wx*wx*mom[3] + wy*wy*mom[4] + wz*wz*mom[5]
           + 2.f*(wx*wy*mom[6] + wx*wz*mom[7] + wy*wz*mom[8]);
  const float invN = 1.0f / (float)TOTROWS;
  float mean = sum1 * invN;
  float var  = ss * invN - mean*mean;
  float sc = rsqrtf(var + 1e-5f) * gamma1[c];
  float sh = beta1[c] - mean * sc;
  sc1[c] = sc; sh1[c] = sh;
  W1s[c] = wx*sc; W1s[64+c] = wy*sc; W1s[128+c] = wz*sc;
}

// ---------------- KD: MFMA main pass (BN1 inline) — R8 version ----------------
// 1024 blocks -> 4096 waves x 4 sites. Per site A1(32x64 bf16) @ W2(64x128).
// a = relu(g*sc + dx*wxs + dy*wys + dz*wzs + sh).
__global__ __launch_bounds__(256, 2) void kD_mfma(
    const float* __restrict__ pos, const int* __restrict__ idx,
    const float* __restrict__ g, const float* __restrict__ sc1,
    const float* __restrict__ sh1, const float* __restrict__ W1s,
    const float* __restrict__ W2,
    float* __restrict__ stats2, float* __restrict__ out_nf)
{
  __shared__ float red2[256];
  red2[threadIdx.x] = 0.f;
  __syncthreads();
  const int lane = threadIdx.x & 63;
  const int quad = lane >> 4;
  const int col  = lane & 15;
  const int gw = (blockIdx.x*256 + threadIdx.x) >> 6;

  bf16x8 Bf[2][8];
  #pragma unroll
  for (int kt = 0; kt < 2; ++kt)
    #pragma unroll
    for (int nt = 0; nt < 8; ++nt) {
      bf16x8 v;
      #pragma unroll
      for (int j = 0; j < 8; ++j)
        v[j] = (__bf16)W2[(kt*32 + quad*8 + j)*CC2 + nt*16 + col];
      Bf[kt][nt] = v;
    }
  float wxs[2][8], wys[2][8], wzs[2][8], scj[2][8], shj[2][8];
  #pragma unroll
  for (int kt = 0; kt < 2; ++kt)
    #pragma unroll
    for (int j = 0; j < 8; ++j) {
      int c = kt*32 + quad*8 + j;
      wxs[kt][j] = W1s[c]; wys[kt][j] = W1s[64+c]; wzs[kt][j] = W1s[128+c];
      scj[kt][j] = sc1[c]; shj[kt][j] = sh1[c];
    }
  float ssum[8], ssq[8];
  #pragma unroll
  for (int nt = 0; nt < 8; ++nt) { ssum[nt] = 0.f; ssq[nt] = 0.f; }

  for (int si = 0; si < 4; ++si) {
    const int site = gw*4 + si;
    const int b = site >> 11;
    const float* pc = pos + (size_t)site*3;
    const float cx = pc[0], cy = pc[1], cz = pc[2];
    int mm[2]; float dx[2], dy[2], dz[2];
    #pragma unroll
    for (int mt = 0; mt < 2; ++mt) {
      mm[mt] = idx[site*KK + mt*16 + col];
      const float* pm = pos + ((size_t)b*NN + mm[mt])*3;
      dx[mt] = pm[0]-cx; dy[mt] = pm[1]-cy; dz[mt] = pm[2]-cz;
    }
    bf16x8 Af[2][2];
    #pragma unroll
    for (int mt = 0; mt < 2; ++mt)
      #pragma unroll
      for (int kt = 0; kt < 2; ++kt) {
        const float4* gp =
          (const float4*)(g + (((size_t)b*NN + mm[mt])*CC1 + kt*32 + quad*8));
        float4 g0 = gp[0], g1 = gp[1];
        float hv[8] = {g0.x,g0.y,g0.z,g0.w,g1.x,g1.y,g1.z,g1.w};
        bf16x8 v;
        #pragma unroll
        for (int j = 0; j < 8; ++j) {
          float t = fmaf(dz[mt], wzs[kt][j],
                    fmaf(dy[mt], wys[kt][j],
                    fmaf(dx[mt], wxs[kt][j], shj[kt][j])));
          float h = fmaf(hv[j], scj[kt][j], t);
          v[j] = (__bf16)fmaxf(h, 0.f);
        }
        Af[mt][kt] = v;
      }
    float mx[8];
    #pragma unroll
    for (int nt = 0; nt < 8; ++nt) mx[nt] = -3.0e38f;
    #pragma unroll
    for (int mt = 0; mt < 2; ++mt) {
      f32x4 acc[8];
      #pragma unroll
      for (int nt = 0; nt < 8; ++nt) {
        f32x4 a = {0.f, 0.f, 0.f, 0.f};
        a = __builtin_amdgcn_mfma_f32_16x16x32_bf16(Af[mt][0], Bf[0][nt], a, 0, 0, 0);
        a = __builtin_amdgcn_mfma_f32_16x16x32_bf16(Af[mt][1], Bf[1][nt], a, 0, 0, 0);
        acc[nt] = a;
      }
      #pragma unroll
      for (int nt = 0; nt < 8; ++nt)
        #pragma unroll
        for (int r = 0; r < 4; ++r) {
          float v = acc[nt][r];
          ssum[nt] += v; ssq[nt] = fmaf(v, v, ssq[nt]);
          mx[nt] = fmaxf(mx[nt], v);
        }
    }
    #pragma unroll
    for (int nt = 0; nt < 8; ++nt) {
      float m = mx[nt];
      m = fmaxf(m, __shfl_xor(m, 16, 64));
      m = fmaxf(m, __shfl_xor(m, 32, 64));
      if ((nt & 3) == quad)
        out_nf[(size_t)site*CC2 + nt*16 + col] = m;   // pre-BN pooled
    }
  }
  #pragma unroll
  for (int nt = 0; nt < 8; ++nt) {
    float s = ssum[nt];
    s += __shfl_xor(s, 16, 64); s += __shfl_xor(s, 32, 64);
    float q = ssq[nt];
    q += __shfl_xor(q, 16, 64); q += __shfl_xor(q, 32, 64);
    if (lane < 16) {
      atomicAdd(&red2[nt*16 + col], s);
      atomicAdd(&red2[128 + nt*16 + col], q);
    }
  }
  __syncthreads();
  unsafeAtomicAdd(&stats2[threadIdx.x], red2[threadIdx.x]);
}

// ---------------- K45: position copy + bn2/relu in place ----------------
// blocks [0,192): copy position (49152 elems); blocks [192,8384): bn2.
__global__ __launch_bounds__(256) void k45_epi(const float* __restrict__ pos,
                                               const float* __restrict__ g2,
                                               const float* __restrict__ be2,
                                               const float* __restrict__ stats2,
                                               float* __restrict__ out)
{
  int i = blockIdx.x*256 + threadIdx.x;
  if (blockIdx.x < 192) { out[i] = pos[i]; return; }
  int j = i - 192*256;
  int c = j & (CC2-1);
  const float invc = 1.0f / (float)TOTROWS;
  float mean = stats2[c] * invc;
  float var  = stats2[128 + c] * invc - mean*mean;
  float sc = rsqrtf(var + 1e-5f) * g2[c];
  float sh = be2[c] - mean * sc;
  float* out_nf = out + (size_t)BB*NN*3;
  float x = out_nf[j];
  out_nf[j] = fmaxf(fmaf(x, sc, sh), 0.f);
}

extern "C" void kernel_launch(void* const* d_in, const int* in_sizes, int n_in,
                              void* d_out, int out_size, void* d_ws, size_t ws_size,
                              hipStream_t stream) {
  const float* pos  = (const float*)d_in[0];
  const float* feat = (const float*)d_in[1];
  const float* W1   = (const float*)d_in[2];
  const float* g1   = (const float*)d_in[3];
  const float* be1  = (const float*)d_in[4];
  const float* W2   = (const float*)d_in[5];
  const float* g2   = (const float*)d_in[6];
  const float* be2  = (const float*)d_in[7];
  float* out = (float*)d_out;
  float* out_nf = out + (size_t)BB*NN*3;

  char* w = (char*)d_ws;
  int*   idx    = (int*)w;                       // 2 MB @ 0
  float* A      = (float*)(w + 0x200000);        // 320
  float* mom    = A + 320;                       // 16
  float* stats2 = mom + 16;                      // 256
  float* sc1    = stats2 + 256;                  // 64
  float* sh1    = sc1 + 64;                      // 64
  float* W1s    = sh1 + 64;                      // 192
  float* cnt    = (float*)(w + 0x210000);        // 16384 each
  float* DXa    = cnt + SITES;
  float* DYa    = DXa + SITES;
  float* DZa    = DYa + SITES;
  float* g      = (float*)(w + 0x260000);        // 4 MB
  float* Pc     = (float*)(w + 0x660000);        // 128*2048 f32 = 1 MB each
  float* Px     = Pc + 128*NN;
  float* Py     = Px + 128*NN;
  float* Pz     = Py + 128*NN;                   // ends ~10.4 MB

  hipMemsetAsync(A, 0, (320 + 16 + 256)*sizeof(float), stream);
  k1_ball   <<<512, 256, 0, stream>>>(pos, idx);
  kP_scatter<<<128, 256, 0, stream>>>(pos, idx, Pc, Px, Py, Pz, mom);
  kR_reduce <<<256, 256, 0, stream>>>(Pc, Px, Py, Pz, cnt, DXa, DYa, DZa);
  kB_g      <<<128, 256, 0, stream>>>(feat, W1, cnt, DXa, DYa, DZa, g, A);
  kS_fold   <<<1, 256, 0, stream>>>(W1, g1, be1, A, mom, sc1, sh1, W1s);
  kD_mfma   <<<1024, 256, 0, stream>>>(pos, idx, g, sc1, sh1, W1s, W2,
                                       stats2, out_nf);
  k45_epi   <<<192 + (SITES*CC2)/256, 256, 0, stream>>>(pos, g2, be2, stats2, out);
}